// Round 1
// baseline (227.396 us; speedup 1.0000x reference)
//
#include <hip/hip_runtime.h>

// SpatialDistangleLoss: loss = sum_p |y_p| * (box5x5(|y|)_p - |y_p|) / 25 / (H*W*B)
// y shape (8, 320, 96, 96) fp32 -> 2560 planes of 96x96.
// R4: FUSED single kernel. Per-plane block computes partial as before (verified
// compute body, bitwise-identical reduction order), then a hierarchical
// last-block-done scheme (32 sub-counters x 80 blocks + 1 master) lets the
// final block reduce the 2560 partials in-kernel. Hierarchy avoids the
// 2560-same-address atomic serialization (~50ns each = ~130us in R1/R2).
// Counters live at ws+NPLANES, zeroed per-replay via graph-capturable
// hipMemsetAsync. Agent-scope (device) atomics handle cross-XCD visibility.

#define HH 96
#define WW 96
#define NPLANES 2560
#define LSTRIDE 100  // floats; %4==0 keeps float4 LDS ops aligned, %32!=0 spreads banks
#define NSUB 32
#define QUOTA (NPLANES / NSUB)  // 80
#define SCALE (1.0f / (25.0f * 96.0f * 96.0f * 8.0f))

__global__ __launch_bounds__(256) void sdl_fused(const float* __restrict__ y,
                                                 float* __restrict__ ws,
                                                 unsigned* __restrict__ cnt,
                                                 float* __restrict__ out) {
    __shared__ float s[HH * LSTRIDE];  // 38400 B
    __shared__ float red[4];
    __shared__ int last_flag;

    const int tid = threadIdx.x;
    const int bid = blockIdx.x;
    const float* base = y + (size_t)bid * (HH * WW);

    // ---- stage plane into LDS as |y| ----
    // 96*96 = 9216 floats = 2304 float4 = 9 per thread, fully coalesced & unique.
#pragma unroll
    for (int k = 0; k < 9; ++k) {
        const int idx = tid + 256 * k;  // 0..2303
        const int row = idx / 24;       // 24 float4 per row
        const int c4  = idx % 24;
        float4 v = *(const float4*)(base + row * WW + c4 * 4);
        float* d = &s[row * LSTRIDE + c4 * 4];
        d[0] = fabsf(v.x);
        d[1] = fabsf(v.y);
        d[2] = fabsf(v.z);
        d[3] = fabsf(v.w);
    }
    __syncthreads();

    // ---- compute from LDS ----
    // 192 active threads: 24 col-groups (4 cols) x 8 row-strips (12 rows).
    float acc = 0.0f;
    if (tid < 192) {
        const int gx    = tid % 24;
        const int strip = tid / 24;  // 0..7
        const bool hl = (gx >= 1);
        const bool hr = (gx <= 22);

        float rs[5][4];  // ring: horizontal 5-sums for the last 5 loaded rows
        float av[3][4];  // ring: center values for the last 3 loaded rows
#pragma unroll
        for (int k = 0; k < 5; ++k)
#pragma unroll
            for (int j = 0; j < 4; ++j) rs[k][j] = 0.0f;
#pragma unroll
        for (int k = 0; k < 3; ++k)
#pragma unroll
            for (int j = 0; j < 4; ++j) av[k][j] = 0.0f;

#pragma unroll
        for (int i = 0; i < 16; ++i) {
            const int ri = strip * 12 - 2 + i;  // row being loaded
            float x[12];                        // cols gx*4-4 .. gx*4+7
            if ((unsigned)ri < (unsigned)HH) {
                const float* rowp = &s[ri * LSTRIDE + gx * 4];
                float4 m = *(const float4*)(rowp);
                float4 l = hl ? *(const float4*)(rowp - 4) : make_float4(0, 0, 0, 0);
                float4 r = hr ? *(const float4*)(rowp + 4) : make_float4(0, 0, 0, 0);
                x[0] = l.x; x[1] = l.y; x[2]  = l.z; x[3]  = l.w;
                x[4] = m.x; x[5] = m.y; x[6]  = m.z; x[7]  = m.w;
                x[8] = r.x; x[9] = r.y; x[10] = r.z; x[11] = r.w;
            } else {
#pragma unroll
                for (int k = 0; k < 12; ++k) x[k] = 0.0f;
            }

#pragma unroll
            for (int j = 0; j < 4; ++j) {
                rs[i % 5][j] = x[j + 2] + x[j + 3] + x[j + 4] + x[j + 5] + x[j + 6];
                av[i % 3][j] = x[j + 4];
            }

            if (i >= 4) {
#pragma unroll
                for (int j = 0; j < 4; ++j) {
                    float box = rs[0][j] + rs[1][j] + rs[2][j] + rs[3][j] + rs[4][j];
                    float a = av[(i - 2) % 3][j];
                    acc += a * (box - a);
                }
            }
        }
    }

    // ---- block reduction -> partial ----
#pragma unroll
    for (int off = 32; off > 0; off >>= 1) acc += __shfl_down(acc, off, 64);
    const int lane = tid & 63;
    const int wid  = tid >> 6;
    if (lane == 0) red[wid] = acc;
    __syncthreads();

    if (tid == 0) {
        const float partial = red[0] + red[1] + red[2] + red[3];
        // agent-scope store -> visible at device coherence point (cross-XCD)
        __hip_atomic_store(&ws[bid], partial, __ATOMIC_RELAXED,
                           __HIP_MEMORY_SCOPE_AGENT);
        int last = 0;
        const unsigned sub = (unsigned)bid & (NSUB - 1);  // 80 blocks per sub-counter
        unsigned p = __hip_atomic_fetch_add(&cnt[sub], 1u, __ATOMIC_ACQ_REL,
                                            __HIP_MEMORY_SCOPE_AGENT);
        if (p == QUOTA - 1) {
            unsigned q = __hip_atomic_fetch_add(&cnt[NSUB], 1u, __ATOMIC_ACQ_REL,
                                                __HIP_MEMORY_SCOPE_AGENT);
            last = (q == NSUB - 1);
        }
        last_flag = last;
    }
    __syncthreads();

    // ---- last block reduces all partials (same summation order as old sdl_finish
    //      -> bitwise-identical result) ----
    if (last_flag) {
        float a2 = 0.0f;
#pragma unroll
        for (int k = 0; k < NPLANES / 256; ++k)
            a2 += __hip_atomic_load(&ws[tid + 256 * k], __ATOMIC_RELAXED,
                                    __HIP_MEMORY_SCOPE_AGENT);
#pragma unroll
        for (int off = 32; off > 0; off >>= 1) a2 += __shfl_down(a2, off, 64);
        if (lane == 0) red[wid] = a2;
        __syncthreads();
        if (tid == 0) {
            out[0] = (red[0] + red[1] + red[2] + red[3]) * SCALE;
        }
    }
}

extern "C" void kernel_launch(void* const* d_in, const int* in_sizes, int n_in,
                              void* d_out, int out_size, void* d_ws, size_t ws_size,
                              hipStream_t stream) {
    const float* y = (const float*)d_in[0];
    float* ws = (float*)d_ws;
    unsigned* cnt = (unsigned*)(ws + NPLANES);
    float* out = (float*)d_out;
    // zero the 33 counters each replay (graph-capturable async memset)
    hipMemsetAsync(cnt, 0, (NSUB + 1) * sizeof(unsigned), stream);
    sdl_fused<<<NPLANES, 256, 0, stream>>>(y, ws, cnt, out);
}

// Round 2
// 142.176 us; speedup vs baseline: 1.5994x; 1.5994x over previous
//
#include <hip/hip_runtime.h>

// SpatialDistangleLoss: loss = sum_p |y_p| * (box5x5(|y|)_p - |y_p|) / 25 / (H*W*B)
// y shape (8, 320, 96, 96) fp32 -> 2560 planes of 96x96.
// R5: back to TWO kernels (R4 fusion regressed 92us: agent-scope ACQ_REL RMWs
// lower to per-XCD L2 writeback/invalidate on gfx950 -> thousands of cache
// flush drains; counters showed 5% HBM / 8% VALU / 25% occ = pure
// serialization). Structure change vs R3 baseline:
//   - HALF-PLANE tiles: 5120 blocks x 192 threads, 52 staged rows
//     (48 out + 2x2 halo), 20.8 KB LDS -> 7 blocks/CU resident (was 4),
//     no idle wave in compute (R3 had 64/256 threads dead), finer tail.
//   - halo rows re-fetched (+8% logical reads, L3-absorbed).
// Kernel B unchanged: single block reduces 5120 partials, writes scaled loss.

#define HH 96
#define WW 96
#define NPLANES 2560
#define TROWS 48           // output rows per tile
#define SROWS 52           // staged rows (2 halo top + 2 bottom)
#define NTILES (NPLANES * 2)
#define LSTRIDE 100        // floats; %4==0 keeps float4 LDS ops aligned, %32!=0 spreads banks
#define SCALE (1.0f / (25.0f * 96.0f * 96.0f * 8.0f))

__global__ __launch_bounds__(192) void sdl_partial(const float* __restrict__ y,
                                                   float* __restrict__ ws) {
    __shared__ float s[SROWS * LSTRIDE];  // 20800 B
    __shared__ float red[3];

    const int tid = threadIdx.x;
    const int bid = blockIdx.x;
    const int plane = bid >> 1;
    const int h0 = (bid & 1) * TROWS;  // 0 or 48
    const float* base = y + (size_t)plane * (HH * WW);

    // ---- stage 52 rows into LDS as |y| (halo rows outside plane -> 0) ----
    // 52*24 = 1248 float4; 192 threads -> 6.5 each.
#pragma unroll
    for (int k = 0; k < 7; ++k) {
        const int idx = tid + 192 * k;  // 0..1343
        if (idx < SROWS * 24) {
            const int row = idx / 24;   // staged row 0..51
            const int c4  = idx % 24;
            const int g   = h0 - 2 + row;  // global plane row
            float4 v = make_float4(0.f, 0.f, 0.f, 0.f);
            if ((unsigned)g < (unsigned)HH) {
                v = *(const float4*)(base + g * WW + c4 * 4);
            }
            float* d = &s[row * LSTRIDE + c4 * 4];
            d[0] = fabsf(v.x);
            d[1] = fabsf(v.y);
            d[2] = fabsf(v.z);
            d[3] = fabsf(v.w);
        }
    }
    __syncthreads();

    // ---- compute from LDS: all 192 threads active ----
    // 24 col-groups (4 cols) x 8 row-strips (6 rows each).
    const int gx    = tid % 24;
    const int strip = tid / 24;  // 0..7
    const bool hl = (gx >= 1);
    const bool hr = (gx <= 22);

    float rs[5][4];  // ring: horizontal 5-sums for the last 5 loaded rows
    float av[3][4];  // ring: center values for the last 3 loaded rows
#pragma unroll
    for (int k = 0; k < 5; ++k)
#pragma unroll
        for (int j = 0; j < 4; ++j) rs[k][j] = 0.0f;
#pragma unroll
    for (int k = 0; k < 3; ++k)
#pragma unroll
        for (int j = 0; j < 4; ++j) av[k][j] = 0.0f;

    float acc = 0.0f;
#pragma unroll
    for (int i = 0; i < 10; ++i) {
        const int lr = strip * 6 + i;  // staged row being loaded, 0..51 (always valid)
        float x[12];                   // cols gx*4-4 .. gx*4+7
        const float* rowp = &s[lr * LSTRIDE + gx * 4];
        float4 m = *(const float4*)(rowp);
        float4 l = hl ? *(const float4*)(rowp - 4) : make_float4(0, 0, 0, 0);
        float4 r = hr ? *(const float4*)(rowp + 4) : make_float4(0, 0, 0, 0);
        x[0] = l.x; x[1] = l.y; x[2]  = l.z; x[3]  = l.w;
        x[4] = m.x; x[5] = m.y; x[6]  = m.z; x[7]  = m.w;
        x[8] = r.x; x[9] = r.y; x[10] = r.z; x[11] = r.w;

#pragma unroll
        for (int j = 0; j < 4; ++j) {
            rs[i % 5][j] = x[j + 2] + x[j + 3] + x[j + 4] + x[j + 5] + x[j + 6];
            av[i % 3][j] = x[j + 4];
        }

        if (i >= 4) {
            // emitting output at staged row lr-2 (= plane row h0 + strip*6 + i-4)
#pragma unroll
            for (int j = 0; j < 4; ++j) {
                float box = rs[0][j] + rs[1][j] + rs[2][j] + rs[3][j] + rs[4][j];
                float a = av[(i - 2) % 3][j];
                acc += a * (box - a);
            }
        }
    }

    // ---- block reduction (3 waves) -> plain store of partial ----
#pragma unroll
    for (int off = 32; off > 0; off >>= 1) acc += __shfl_down(acc, off, 64);
    const int lane = tid & 63;
    const int wid  = tid >> 6;
    if (lane == 0) red[wid] = acc;
    __syncthreads();
    if (tid == 0) {
        ws[bid] = red[0] + red[1] + red[2];
    }
}

__global__ __launch_bounds__(256) void sdl_finish(const float* __restrict__ ws,
                                                  float* __restrict__ out) {
    const int tid = threadIdx.x;
    float acc = 0.0f;
#pragma unroll
    for (int k = 0; k < NTILES / 256; ++k) acc += ws[tid + 256 * k];
#pragma unroll
    for (int off = 32; off > 0; off >>= 1) acc += __shfl_down(acc, off, 64);
    __shared__ float red[4];
    const int lane = tid & 63;
    const int wid  = tid >> 6;
    if (lane == 0) red[wid] = acc;
    __syncthreads();
    if (tid == 0) {
        out[0] = (red[0] + red[1] + red[2] + red[3]) * SCALE;
    }
}

extern "C" void kernel_launch(void* const* d_in, const int* in_sizes, int n_in,
                              void* d_out, int out_size, void* d_ws, size_t ws_size,
                              hipStream_t stream) {
    const float* y = (const float*)d_in[0];
    float* ws = (float*)d_ws;
    float* out = (float*)d_out;
    sdl_partial<<<NTILES, 192, 0, stream>>>(y, ws);
    sdl_finish<<<1, 256, 0, stream>>>(ws, out);
}

// Round 3
// 136.446 us; speedup vs baseline: 1.6666x; 1.0420x over previous
//
#include <hip/hip_runtime.h>

// SpatialDistangleLoss: loss = sum_p |y_p| * (box5x5(|y|)_p - |y_p|) / 25 / (H*W*B)
// y shape (8, 320, 96, 96) fp32 -> 2560 planes of 96x96.
// R6 = revert to R3 (best measured: 135.1us). Session evidence:
//   - Timed window contains two harness-side 377MB workspace-poison fills
//     (~57.5us each at 82% HBM peak) = ~115us floor we cannot touch.
//   - Controllable floor: 94.4MB input read @6.3TB/s ~= 15us + finish ~2.5us.
//     R3 sits ~2us above it (~1.5%).
//   - R4 (fused, last-block-done w/ agent-scope acq_rel): +92us. Agent-scope
//     RMWs lower to per-XCD L2 writeback/invalidate on gfx950 -> serialization
//     (counters: 5% HBM, 8% VALU, 25% occ).
//   - R5 (half-plane tiles): +7us. Rolling-window warmup fraction doubled
//     (25%->40% of LDS iterations) + 8% halo re-fetch; occupancy was not the
//     bottleneck (already latency-hidden at 16 waves/CU).
// Kernel A: one block per plane, stage |y| into LDS, separable 5x5 box,
//           per-block partial -> d_ws[blockIdx] (plain store, NO atomics:
//           2560 same-address atomicAdds serialized at ~50ns each = ~130us in R1/R2).
// Kernel B: single block reduces 2560 partials, writes scaled loss.

#define HH 96
#define WW 96
#define NPLANES 2560
#define LSTRIDE 100  // floats; %4==0 keeps float4 LDS ops aligned, %32!=0 spreads banks
#define SCALE (1.0f / (25.0f * 96.0f * 96.0f * 8.0f))

__global__ __launch_bounds__(256) void sdl_partial(const float* __restrict__ y,
                                                   float* __restrict__ ws) {
    __shared__ float s[HH * LSTRIDE];  // 38400 B
    __shared__ float red[4];

    const int tid = threadIdx.x;
    const float* base = y + (size_t)blockIdx.x * (HH * WW);

    // ---- stage plane into LDS as |y| ----
    // 96*96 = 9216 floats = 2304 float4 = 9 per thread, fully coalesced & unique.
#pragma unroll
    for (int k = 0; k < 9; ++k) {
        const int idx = tid + 256 * k;  // 0..2303
        const int row = idx / 24;       // 24 float4 per row
        const int c4  = idx % 24;
        float4 v = *(const float4*)(base + row * WW + c4 * 4);
        float* d = &s[row * LSTRIDE + c4 * 4];
        d[0] = fabsf(v.x);
        d[1] = fabsf(v.y);
        d[2] = fabsf(v.z);
        d[3] = fabsf(v.w);
    }
    __syncthreads();

    // ---- compute from LDS ----
    // 192 active threads: 24 col-groups (4 cols) x 8 row-strips (12 rows).
    float acc = 0.0f;
    if (tid < 192) {
        const int gx    = tid % 24;
        const int strip = tid / 24;  // 0..7
        const bool hl = (gx >= 1);
        const bool hr = (gx <= 22);

        float rs[5][4];  // ring: horizontal 5-sums for the last 5 loaded rows
        float av[3][4];  // ring: center values for the last 3 loaded rows
#pragma unroll
        for (int k = 0; k < 5; ++k)
#pragma unroll
            for (int j = 0; j < 4; ++j) rs[k][j] = 0.0f;
#pragma unroll
        for (int k = 0; k < 3; ++k)
#pragma unroll
            for (int j = 0; j < 4; ++j) av[k][j] = 0.0f;

#pragma unroll
        for (int i = 0; i < 16; ++i) {
            const int ri = strip * 12 - 2 + i;  // row being loaded
            float x[12];                        // cols gx*4-4 .. gx*4+7
            if ((unsigned)ri < (unsigned)HH) {
                const float* rowp = &s[ri * LSTRIDE + gx * 4];
                float4 m = *(const float4*)(rowp);
                float4 l = hl ? *(const float4*)(rowp - 4) : make_float4(0, 0, 0, 0);
                float4 r = hr ? *(const float4*)(rowp + 4) : make_float4(0, 0, 0, 0);
                x[0] = l.x; x[1] = l.y; x[2]  = l.z; x[3]  = l.w;
                x[4] = m.x; x[5] = m.y; x[6]  = m.z; x[7]  = m.w;
                x[8] = r.x; x[9] = r.y; x[10] = r.z; x[11] = r.w;
            } else {
#pragma unroll
                for (int k = 0; k < 12; ++k) x[k] = 0.0f;
            }

#pragma unroll
            for (int j = 0; j < 4; ++j) {
                rs[i % 5][j] = x[j + 2] + x[j + 3] + x[j + 4] + x[j + 5] + x[j + 6];
                av[i % 3][j] = x[j + 4];
            }

            if (i >= 4) {
#pragma unroll
                for (int j = 0; j < 4; ++j) {
                    float box = rs[0][j] + rs[1][j] + rs[2][j] + rs[3][j] + rs[4][j];
                    float a = av[(i - 2) % 3][j];
                    acc += a * (box - a);
                }
            }
        }
    }

    // ---- block reduction -> plain store of partial ----
#pragma unroll
    for (int off = 32; off > 0; off >>= 1) acc += __shfl_down(acc, off, 64);
    const int lane = tid & 63;
    const int wid  = tid >> 6;
    if (lane == 0) red[wid] = acc;
    __syncthreads();
    if (tid == 0) {
        ws[blockIdx.x] = red[0] + red[1] + red[2] + red[3];
    }
}

__global__ __launch_bounds__(256) void sdl_finish(const float* __restrict__ ws,
                                                  float* __restrict__ out) {
    const int tid = threadIdx.x;
    float acc = 0.0f;
#pragma unroll
    for (int k = 0; k < NPLANES / 256; ++k) acc += ws[tid + 256 * k];
#pragma unroll
    for (int off = 32; off > 0; off >>= 1) acc += __shfl_down(acc, off, 64);
    __shared__ float red[4];
    const int lane = tid & 63;
    const int wid  = tid >> 6;
    if (lane == 0) red[wid] = acc;
    __syncthreads();
    if (tid == 0) {
        out[0] = (red[0] + red[1] + red[2] + red[3]) * SCALE;
    }
}

extern "C" void kernel_launch(void* const* d_in, const int* in_sizes, int n_in,
                              void* d_out, int out_size, void* d_ws, size_t ws_size,
                              hipStream_t stream) {
    const float* y = (const float*)d_in[0];
    float* ws = (float*)d_ws;
    float* out = (float*)d_out;
    sdl_partial<<<NPLANES, 256, 0, stream>>>(y, ws);
    sdl_finish<<<1, 256, 0, stream>>>(ws, out);
}